// Round 7
// baseline (529.149 us; speedup 1.0000x reference)
//
#include <hip/hip_runtime.h>
#include <hip/hip_bf16.h>

// SeqExperts: 64 experts, 128 tokens each, d_model=1024, d_hidden=4096.
// out[e*128+m] = relu(x_e @ W1[e]^T) @ W2[e]^T
// R3 (540us): counted-vmcnt double-buffer, XCD swizzle, BK=32.
// R4 (794us FAIL): no-LDS direct-fragment. R5 (707us FAIL): broken staging coalescing.
// R6 (521us): BK=64 + chunk-XOR LDS swizzle + cheap pack2 cvt + nontemporal W + x->bf16 prepass.
// R7: pipeline depth 3 (4 named register sets, unroll-4 K-loop, BK=32):
//     each tile's vmcnt wait targets loads issued 3 phases earlier; ~144 KB/CU
//     stays in flight across barriers (T3/T4: never drain, counted waits).

typedef __attribute__((ext_vector_type(8))) short bf16x8;   // 8 bf16 (4 VGPRs)
typedef __attribute__((ext_vector_type(4))) float f32x4;
typedef __attribute__((ext_vector_type(4))) unsigned int u32x4;

#define N_EXPERTS 64
#define DM 1024
#define DH 4096
#define TOKS 128

__device__ __forceinline__ unsigned f2u(float f) {
    union { float f; unsigned u; } v; v.f = f; return v.u;
}
// round-half-up fp32->bf16 (0.5 ulp; no NaN/inf in data)
__device__ __forceinline__ unsigned short f2bf(float f) {
    return (unsigned short)((f2u(f) + 0x8000u) >> 16);
}
// pack two fp32 -> 2xbf16 in one u32
__device__ __forceinline__ unsigned pack2(float lo, float hi) {
    return ((f2u(lo) + 0x8000u) >> 16) | ((f2u(hi) + 0x8000u) & 0xFFFF0000u);
}

// elementwise fp32 -> bf16 (8 elems/thread)
__global__ __launch_bounds__(256)
void cvt_bf16(const float* __restrict__ in, unsigned* __restrict__ outp, int n8) {
    int i = blockIdx.x * blockDim.x + threadIdx.x;
    if (i >= n8) return;
    const f32x4* p = (const f32x4*)in + (size_t)i * 2;
    f32x4 a = p[0], b = p[1];
    u32x4 o = { pack2(a[0], a[1]), pack2(a[2], a[3]),
                pack2(b[0], b[1]), pack2(b[2], b[3]) };
    *((u32x4*)outp + i) = o;
}

// C[128 x N] = A[128 x K] * B[N x K]^T for expert e.
// A: bf16 row-major lda=K. B: fp32 weights [N][K]. C: bf16+relu or fp32.
// LDS tiles [128][32] bf16 (64B rows, 4 chunks of 16B), chunk c stored at c^((row>>1)&3).
template<int N, int K, bool RELU_OUT_BF16>
__global__ __launch_bounds__(256, 2)
void moe_gemm(const unsigned short* __restrict__ Ab, const float* __restrict__ Bp,
              void* __restrict__ Cp, int nwg_per_xcd)
{
    constexpr int BK = 32;          // K elems per tile
    constexpr int NT = K / BK;      // 32 (pass1) / 128 (pass2); % 4 == 0
    constexpr int NTILES = N / 128;

    __shared__ unsigned short sA[2][128][BK];  // 8 KiB per buf
    __shared__ unsigned short sB[2][128][BK];

    const int tid = threadIdx.x;
    const int bid = (blockIdx.x & 7) * nwg_per_xcd + (blockIdx.x >> 3);
    const int e   = bid / NTILES;
    const int nt  = bid % NTILES;

    const int lane = tid & 63;
    const int w    = tid >> 6;       // wave 0..3
    const int wr   = w >> 1;
    const int wc   = w & 1;
    const int lrow = lane & 15;
    const int kq   = lane >> 4;      // 0..3

    // ---- staging: arow = tid>>2 (0..63; rows arow, arow+64), ac = tid&3 (16B chunk).
    //     Per instruction: 4 lanes cover a row's full 64B (A) / strided pair covers 128B (B).
    const int arow = tid >> 2;
    const int ac   = tid & 3;
    const int aswz = (arow >> 1) & 3;    // (arow+64) gives same &3 -> j-independent

    const unsigned short* aBase = Ab + (size_t)(e * TOKS + arow) * K + ac * 8;
    const float*          bBase = Bp + ((size_t)e * N + (size_t)nt * 128 + arow) * K + ac * 8;

    // ---- fragment-read chunk offset (per-lane constant); frag rows: (lrow>>1)&3 only.
    const int offk = ((kq ^ ((lrow >> 1) & 3))) * 8;

    f32x4 acc[4][4];
    #pragma unroll
    for (int i = 0; i < 4; ++i)
        #pragma unroll
        for (int n = 0; n < 4; ++n)
            #pragma unroll
            for (int q = 0; q < 4; ++q) acc[i][n][q] = 0.f;

    struct SetA { u32x4 a[2]; };                 // rows arow, arow+64 (16B each)
    struct SetB { f32x4 b[4]; };                 // 2 rows x 2 float4 (32B fp32 each row)
    SetA sa0, sa1, sa2, sa3;
    SetB sb0, sb1, sb2, sb3;

    auto LOAD = [&](int t, SetA& A, SetB& B) {
        #pragma unroll
        for (int j = 0; j < 2; ++j)
            A.a[j] = *(const u32x4*)(aBase + (size_t)j * 64 * K + t * BK);
        #pragma unroll
        for (int j = 0; j < 2; ++j) {
            const f32x4* p = (const f32x4*)(bBase + (size_t)j * 64 * K + t * BK);
            B.b[2 * j]     = __builtin_nontemporal_load(p);      // weights: read-once
            B.b[2 * j + 1] = __builtin_nontemporal_load(p + 1);
        }
    };

    auto WRITE = [&](int buf, SetA& A, SetB& B) {
        const int c8 = (ac ^ aswz) * 8;
        #pragma unroll
        for (int j = 0; j < 2; ++j)
            *(u32x4*)&sA[buf][arow + j * 64][c8] = A.a[j];
        #pragma unroll
        for (int j = 0; j < 2; ++j) {
            f32x4 lo = B.b[2 * j], hi = B.b[2 * j + 1];
            u32x4 u = { pack2(lo[0], lo[1]), pack2(lo[2], lo[3]),
                        pack2(hi[0], hi[1]), pack2(hi[2], hi[3]) };
            *(u32x4*)&sB[buf][arow + j * 64][c8] = u;
        }
    };

    auto COMPUTE = [&](int buf) {
        bf16x8 af[4], bfr[4];
        #pragma unroll
        for (int i = 0; i < 4; ++i)
            af[i] = *(const bf16x8*)&sA[buf][wr * 64 + i * 16 + lrow][offk];
        #pragma unroll
        for (int n = 0; n < 4; ++n)
            bfr[n] = *(const bf16x8*)&sB[buf][wc * 64 + n * 16 + lrow][offk];
        #pragma unroll
        for (int i = 0; i < 4; ++i)
            #pragma unroll
            for (int n = 0; n < 4; ++n)
                acc[i][n] = __builtin_amdgcn_mfma_f32_16x16x32_bf16(af[i], bfr[n], acc[i][n], 0, 0, 0);
    };

    // Prologue: 3 tiles in flight before the first barrier (prefetch distance 3).
    LOAD(0, sa0, sb0);
    LOAD(1, sa1, sb1);
    LOAD(2, sa2, sb2);
    WRITE(0, sa0, sb0);                    // counted vmcnt: waits only set 0
    asm volatile("s_waitcnt lgkmcnt(0)" ::: "memory");
    __builtin_amdgcn_s_barrier();

    for (int t = 0; t < NT; t += 4) {
        // phase 0: compute tile t (buf0)
        if (t + 3 < NT) LOAD(t + 3, sa3, sb3);
        COMPUTE(0);
        WRITE(1, sa1, sb1);                // tile t+1 -> buf1 (loads issued 3 phases ago)
        asm volatile("s_waitcnt lgkmcnt(0)" ::: "memory");
        __builtin_amdgcn_s_barrier();

        // phase 1: compute tile t+1 (buf1)
        if (t + 4 < NT) LOAD(t + 4, sa0, sb0);
        COMPUTE(1);
        if (t + 2 < NT) WRITE(0, sa2, sb2);
        asm volatile("s_waitcnt lgkmcnt(0)" ::: "memory");
        __builtin_amdgcn_s_barrier();

        // phase 2: compute tile t+2 (buf0)
        if (t + 5 < NT) LOAD(t + 5, sa1, sb1);
        COMPUTE(0);
        if (t + 3 < NT) WRITE(1, sa3, sb3);
        asm volatile("s_waitcnt lgkmcnt(0)" ::: "memory");
        __builtin_amdgcn_s_barrier();

        // phase 3: compute tile t+3 (buf1)
        if (t + 6 < NT) LOAD(t + 6, sa2, sb2);
        COMPUTE(1);
        if (t + 4 < NT) WRITE(0, sa0, sb0);
        asm volatile("s_waitcnt lgkmcnt(0)" ::: "memory");
        __builtin_amdgcn_s_barrier();
    }

    // Epilogue. C/D layout (m89-verified): col = lane&15, row = (lane>>4)*4 + reg
    const size_t crow0 = (size_t)e * TOKS;
    if constexpr (RELU_OUT_BF16) {
        unsigned short* C = (unsigned short*)Cp;
        #pragma unroll
        for (int i = 0; i < 4; ++i)
            #pragma unroll
            for (int n = 0; n < 4; ++n)
                #pragma unroll
                for (int q = 0; q < 4; ++q) {
                    const int row = wr * 64 + i * 16 + kq * 4 + q;
                    const int col = nt * 128 + wc * 64 + n * 16 + lrow;
                    C[(crow0 + row) * N + col] = f2bf(fmaxf(acc[i][n][q], 0.f));
                }
    } else {
        float* C = (float*)Cp;
        #pragma unroll
        for (int i = 0; i < 4; ++i)
            #pragma unroll
            for (int n = 0; n < 4; ++n)
                #pragma unroll
                for (int q = 0; q < 4; ++q) {
                    const int row = wr * 64 + i * 16 + kq * 4 + q;
                    const int col = nt * 128 + wc * 64 + n * 16 + lrow;
                    C[(crow0 + row) * N + col] = acc[i][n][q];
                }
    }
}

extern "C" void kernel_launch(void* const* d_in, const int* in_sizes, int n_in,
                              void* d_out, int out_size, void* d_ws, size_t ws_size,
                              hipStream_t stream) {
    const float* inputs = (const float*)d_in[0];   // [8192, 1024] fp32
    const float* w1     = (const float*)d_in[1];   // [64, 4096, 1024] fp32
    const float* w2     = (const float*)d_in[2];   // [64, 1024, 4096] fp32
    // d_in[3] = splits (always 128) -- unused

    unsigned short* h  = (unsigned short*)d_ws;                                     // 64 MiB
    unsigned short* xb = (unsigned short*)((char*)d_ws + (size_t)64 * 1024 * 1024); // 16 MiB
    float* out = (float*)d_out;

    // Pre-pass: x fp32 -> bf16
    const int n8 = (TOKS * N_EXPERTS) * DM / 8;    // 1,048,576
    cvt_bf16<<<dim3(n8 / 256), dim3(256), 0, stream>>>(inputs, (unsigned*)xb, n8);

    // Pass 1: h = relu(x @ w1^T), bf16. grid = 64*32 = 2048
    moe_gemm<DH, DM, true><<<dim3(N_EXPERTS * (DH / 128)), dim3(256), 0, stream>>>(
        xb, w1, h, N_EXPERTS * (DH / 128) / 8);
    // Pass 2: out = h @ w2^T, fp32. grid = 64*8 = 512
    moe_gemm<DM, DH, false><<<dim3(N_EXPERTS * (DM / 128)), dim3(256), 0, stream>>>(
        h, w2, out, N_EXPERTS * (DM / 128) / 8);
}